// Round 12
// baseline (30.867 us; speedup 1.0000x reference)
//
#include <hip/hip_runtime.h>
#include <hip/hip_bf16.h>

#define IMG_H 512
#define IMG_W 512
#define NBLOCKS 768
#define TOTAL_ELEMS (48LL * 512 * 512)   // 16*3*512*512

__device__ __forceinline__ float fast_sqrtf(float x) {
    float r; asm("v_sqrt_f32 %0, %1" : "=v"(r) : "v"(x)); return r;   // ~1 ulp
}

__device__ __forceinline__ void load8(const float* __restrict__ p, float v[8]) {
    const float4 x = *reinterpret_cast<const float4*>(p);
    const float4 y = *reinterpret_cast<const float4*>(p + 4);
    v[0] = x.x; v[1] = x.y; v[2] = x.z; v[3] = x.w;
    v[4] = y.x; v[5] = y.y; v[6] = y.z; v[7] = y.w;
}

__device__ __forceinline__ void lds_read8(const float* __restrict__ s, float v[8]) {
    const float4 x = *reinterpret_cast<const float4*>(s);
    const float4 y = *reinterpret_cast<const float4*>(s + 4);
    v[0] = x.x; v[1] = x.y; v[2] = x.z; v[3] = x.w;
    v[4] = y.x; v[5] = y.y; v[6] = y.z; v[7] = y.w;
}

// Separable Sobel magnitude for one output row (8 px/lane); column halo via
// 2 shuffles on the linear vertical-pass terms (zero pad at image edges).
__device__ __forceinline__ void sobel_mag_row(const float t[8], const float m[8], const float b[8],
                                              int lane, float mag[8]) {
    float cs[8], rd[8];
#pragma unroll
    for (int j = 0; j < 8; ++j) {
        cs[j] = (t[j] + b[j]) + 2.0f * m[j];   // vertical [1,2,1]
        rd[j] = b[j] - t[j];                   // vertical [-1,0,1]
    }
    float csL = __shfl_up(cs[7], 1), csR = __shfl_down(cs[0], 1);
    float rdL = __shfl_up(rd[7], 1), rdR = __shfl_down(rd[0], 1);
    if (lane == 0)  { csL = 0.0f; rdL = 0.0f; }
    if (lane == 63) { csR = 0.0f; rdR = 0.0f; }
#pragma unroll
    for (int j = 0; j < 8; ++j) {
        const float ex = ((j == 7) ? csR : cs[j + 1]) - ((j == 0) ? csL : cs[j - 1]);
        const float ey = ((j == 0) ? rdL : rd[j - 1]) + 2.0f * rd[j] + ((j == 7) ? rdR : rd[j + 1]);
        mag[j] = fast_sqrtf(fmaf(ex, ex, fmaf(ey, ey, 1e-6f)));
    }
}

// R9 body verbatim (best measured: 24.3 us). Only the tail differs: one
// atomicAdd(out) per block replaces the slot store + finalize kernel
// (atomic tails were benign in R1-R4; ticket/last-block tails were not).
__global__ __launch_bounds__(512) void edge_loss_kernel(const float* __restrict__ img1,
                                                        const float* __restrict__ img2,
                                                        float* __restrict__ out) {
    const int t = threadIdx.x;
    const int lane = t & 63;
    const int w = t >> 6;                           // 0..7
    const int bid = blockIdx.x;
    const int swz = (bid & 7) * 96 + (bid >> 3);    // bijective XCD swizzle (768=8*96)
    const int plane = swz >> 4;                     // 16 blocks per plane
    const int blk = swz & 15;
    const int yb = blk << 5;                        // tile top row (32-row tile)
    const int y0 = yb + (w << 2);                   // this wave's first row
    const int x0 = lane << 3;
    const size_t base = (size_t)plane * (IMG_H * IMG_W);
    const float* p1 = img1 + base + x0;
    const float* p2 = img2 + base + x0;

    __shared__ float sh[2][8][2][IMG_W];            // 64 KB halo-exchange
    __shared__ float wave_sums[8];

    float a[4][8], b[4][8];
#pragma unroll
    for (int r = 0; r < 4; ++r) {
        load8(p1 + (size_t)(y0 + r) * IMG_W, a[r]);
        load8(p2 + (size_t)(y0 + r) * IMG_W, b[r]);
    }

    float ha[8], hb[8];
    bool hzero = false;
    if (w == 0) {
        hzero = (yb == 0);
        const int y = hzero ? 0 : yb - 1;
        load8(p1 + (size_t)y * IMG_W, ha);
        load8(p2 + (size_t)y * IMG_W, hb);
    } else if (w == 7) {
        hzero = (yb + 32 == IMG_H);
        const int y = hzero ? IMG_H - 1 : yb + 32;
        load8(p1 + (size_t)y * IMG_W, ha);
        load8(p2 + (size_t)y * IMG_W, hb);
    }
    if ((w == 0 || w == 7) && hzero) {
#pragma unroll
        for (int j = 0; j < 8; ++j) { ha[j] = 0.0f; hb[j] = 0.0f; }
    }

    *reinterpret_cast<float4*>(&sh[0][w][0][x0])     = make_float4(a[0][0], a[0][1], a[0][2], a[0][3]);
    *reinterpret_cast<float4*>(&sh[0][w][0][x0 + 4]) = make_float4(a[0][4], a[0][5], a[0][6], a[0][7]);
    *reinterpret_cast<float4*>(&sh[0][w][1][x0])     = make_float4(a[3][0], a[3][1], a[3][2], a[3][3]);
    *reinterpret_cast<float4*>(&sh[0][w][1][x0 + 4]) = make_float4(a[3][4], a[3][5], a[3][6], a[3][7]);
    *reinterpret_cast<float4*>(&sh[1][w][0][x0])     = make_float4(b[0][0], b[0][1], b[0][2], b[0][3]);
    *reinterpret_cast<float4*>(&sh[1][w][0][x0 + 4]) = make_float4(b[0][4], b[0][5], b[0][6], b[0][7]);
    *reinterpret_cast<float4*>(&sh[1][w][1][x0])     = make_float4(b[3][0], b[3][1], b[3][2], b[3][3]);
    *reinterpret_cast<float4*>(&sh[1][w][1][x0 + 4]) = make_float4(b[3][4], b[3][5], b[3][6], b[3][7]);
    __syncthreads();

    // assemble halo rows: top = row y0-1, bot = row y0+4 (per image)
    float ta[8], tb[8], ba[8], bb[8];
    if (w == 0) {
#pragma unroll
        for (int j = 0; j < 8; ++j) { ta[j] = ha[j]; tb[j] = hb[j]; }
    } else {
        lds_read8(&sh[0][w - 1][1][x0], ta);
        lds_read8(&sh[1][w - 1][1][x0], tb);
    }
    if (w == 7) {
#pragma unroll
        for (int j = 0; j < 8; ++j) { ba[j] = ha[j]; bb[j] = hb[j]; }
    } else {
        lds_read8(&sh[0][w + 1][0][x0], ba);
        lds_read8(&sh[1][w + 1][0][x0], bb);
    }

    // image 1 magnitudes, then image 2 + abs-diff accumulate
    float m1[4][8];
    sobel_mag_row(ta,   a[0], a[1], lane, m1[0]);
    sobel_mag_row(a[0], a[1], a[2], lane, m1[1]);
    sobel_mag_row(a[1], a[2], a[3], lane, m1[2]);
    sobel_mag_row(a[2], a[3], ba,   lane, m1[3]);

    float sum = 0.0f;
    {
        float m2[8];
        sobel_mag_row(tb,   b[0], b[1], lane, m2);
#pragma unroll
        for (int j = 0; j < 8; ++j) sum += fabsf(m1[0][j] - m2[j]);
        sobel_mag_row(b[0], b[1], b[2], lane, m2);
#pragma unroll
        for (int j = 0; j < 8; ++j) sum += fabsf(m1[1][j] - m2[j]);
        sobel_mag_row(b[1], b[2], b[3], lane, m2);
#pragma unroll
        for (int j = 0; j < 8; ++j) sum += fabsf(m1[2][j] - m2[j]);
        sobel_mag_row(b[2], b[3], bb,   lane, m2);
#pragma unroll
        for (int j = 0; j < 8; ++j) sum += fabsf(m1[3][j] - m2[j]);
    }

#pragma unroll
    for (int off = 32; off > 0; off >>= 1) sum += __shfl_down(sum, off);

    if (lane == 0) wave_sums[w] = sum;
    __syncthreads();
    if (t == 0) {
        float s = 0.0f;
#pragma unroll
        for (int i = 0; i < 8; ++i) s += wave_sums[i];
        atomicAdd(out, s * (1.0f / (float)TOTAL_ELEMS));   // device-scope, 768 staggered adds
    }
}

extern "C" void kernel_launch(void* const* d_in, const int* in_sizes, int n_in,
                              void* d_out, int out_size, void* d_ws, size_t ws_size,
                              hipStream_t stream) {
    const float* img1 = (const float*)d_in[0];
    const float* img2 = (const float*)d_in[1];
    float* out = (float*)d_out;

    hipMemsetAsync(out, 0, sizeof(float), stream);   // capture-safe memset node
    edge_loss_kernel<<<dim3(NBLOCKS), 512, 0, stream>>>(img1, img2, out);
}

// Round 13
// 24.489 us; speedup vs baseline: 1.2604x; 1.2604x over previous
//
#include <hip/hip_runtime.h>
#include <hip/hip_bf16.h>

#define IMG_H 512
#define IMG_W 512
#define NBLOCKS 768
#define TOTAL_ELEMS (48LL * 512 * 512)   // 16*3*512*512

__device__ __forceinline__ float fast_sqrtf(float x) {
    float r; asm("v_sqrt_f32 %0, %1" : "=v"(r) : "v"(x)); return r;   // ~1 ulp
}

__device__ __forceinline__ void load8(const float* __restrict__ p, float v[8]) {
    const float4 x = *reinterpret_cast<const float4*>(p);
    const float4 y = *reinterpret_cast<const float4*>(p + 4);
    v[0] = x.x; v[1] = x.y; v[2] = x.z; v[3] = x.w;
    v[4] = y.x; v[5] = y.y; v[6] = y.z; v[7] = y.w;
}

__device__ __forceinline__ void lds_read8(const float* __restrict__ s, float v[8]) {
    const float4 x = *reinterpret_cast<const float4*>(s);
    const float4 y = *reinterpret_cast<const float4*>(s + 4);
    v[0] = x.x; v[1] = x.y; v[2] = x.z; v[3] = x.w;
    v[4] = y.x; v[5] = y.y; v[6] = y.z; v[7] = y.w;
}

// Separable Sobel magnitude for one output row (8 px/lane); column halo via
// 2 shuffles on the linear vertical-pass terms (zero pad at image edges).
__device__ __forceinline__ void sobel_mag_row(const float t[8], const float m[8], const float b[8],
                                              int lane, float mag[8]) {
    float cs[8], rd[8];
#pragma unroll
    for (int j = 0; j < 8; ++j) {
        cs[j] = (t[j] + b[j]) + 2.0f * m[j];   // vertical [1,2,1]
        rd[j] = b[j] - t[j];                   // vertical [-1,0,1]
    }
    float csL = __shfl_up(cs[7], 1), csR = __shfl_down(cs[0], 1);
    float rdL = __shfl_up(rd[7], 1), rdR = __shfl_down(rd[0], 1);
    if (lane == 0)  { csL = 0.0f; rdL = 0.0f; }
    if (lane == 63) { csR = 0.0f; rdR = 0.0f; }
#pragma unroll
    for (int j = 0; j < 8; ++j) {
        const float ex = ((j == 7) ? csR : cs[j + 1]) - ((j == 0) ? csL : cs[j - 1]);
        const float ey = ((j == 0) ? rdL : rd[j - 1]) + 2.0f * rd[j] + ((j == 7) ? rdR : rd[j + 1]);
        mag[j] = fast_sqrtf(fmaf(ex, ex, fmaf(ey, ey, 1e-6f)));
    }
}

// R9 verbatim — best measured configuration (24.3 us). Tile = 32 rows
// (8 waves x 4 rows, 512 threads); halo amplification 34/32 = 1.0625x;
// LDS 64 KB -> 2 blocks/CU = 16 waves/CU. Grid 768 = 8 XCDs * 96, swizzled.
__global__ __launch_bounds__(512) void edge_loss_kernel(const float* __restrict__ img1,
                                                        const float* __restrict__ img2,
                                                        float* __restrict__ slots) {
    const int t = threadIdx.x;
    const int lane = t & 63;
    const int w = t >> 6;                           // 0..7
    const int bid = blockIdx.x;
    const int swz = (bid & 7) * 96 + (bid >> 3);    // bijective XCD swizzle (768=8*96)
    const int plane = swz >> 4;                     // 16 blocks per plane
    const int blk = swz & 15;
    const int yb = blk << 5;                        // tile top row (32-row tile)
    const int y0 = yb + (w << 2);                   // this wave's first row
    const int x0 = lane << 3;
    const size_t base = (size_t)plane * (IMG_H * IMG_W);
    const float* p1 = img1 + base + x0;
    const float* p2 = img2 + base + x0;

    __shared__ float sh[2][8][2][IMG_W];            // 64 KB halo-exchange
    __shared__ float wave_sums[8];

    float a[4][8], b[4][8];
#pragma unroll
    for (int r = 0; r < 4; ++r) {
        load8(p1 + (size_t)(y0 + r) * IMG_W, a[r]);
        load8(p2 + (size_t)(y0 + r) * IMG_W, b[r]);
    }

    float ha[8], hb[8];
    bool hzero = false;
    if (w == 0) {
        hzero = (yb == 0);
        const int y = hzero ? 0 : yb - 1;
        load8(p1 + (size_t)y * IMG_W, ha);
        load8(p2 + (size_t)y * IMG_W, hb);
    } else if (w == 7) {
        hzero = (yb + 32 == IMG_H);
        const int y = hzero ? IMG_H - 1 : yb + 32;
        load8(p1 + (size_t)y * IMG_W, ha);
        load8(p2 + (size_t)y * IMG_W, hb);
    }
    if ((w == 0 || w == 7) && hzero) {
#pragma unroll
        for (int j = 0; j < 8; ++j) { ha[j] = 0.0f; hb[j] = 0.0f; }
    }

    *reinterpret_cast<float4*>(&sh[0][w][0][x0])     = make_float4(a[0][0], a[0][1], a[0][2], a[0][3]);
    *reinterpret_cast<float4*>(&sh[0][w][0][x0 + 4]) = make_float4(a[0][4], a[0][5], a[0][6], a[0][7]);
    *reinterpret_cast<float4*>(&sh[0][w][1][x0])     = make_float4(a[3][0], a[3][1], a[3][2], a[3][3]);
    *reinterpret_cast<float4*>(&sh[0][w][1][x0 + 4]) = make_float4(a[3][4], a[3][5], a[3][6], a[3][7]);
    *reinterpret_cast<float4*>(&sh[1][w][0][x0])     = make_float4(b[0][0], b[0][1], b[0][2], b[0][3]);
    *reinterpret_cast<float4*>(&sh[1][w][0][x0 + 4]) = make_float4(b[0][4], b[0][5], b[0][6], b[0][7]);
    *reinterpret_cast<float4*>(&sh[1][w][1][x0])     = make_float4(b[3][0], b[3][1], b[3][2], b[3][3]);
    *reinterpret_cast<float4*>(&sh[1][w][1][x0 + 4]) = make_float4(b[3][4], b[3][5], b[3][6], b[3][7]);
    __syncthreads();

    // assemble halo rows: top = row y0-1, bot = row y0+4 (per image)
    float ta[8], tb[8], ba[8], bb[8];
    if (w == 0) {
#pragma unroll
        for (int j = 0; j < 8; ++j) { ta[j] = ha[j]; tb[j] = hb[j]; }
    } else {
        lds_read8(&sh[0][w - 1][1][x0], ta);
        lds_read8(&sh[1][w - 1][1][x0], tb);
    }
    if (w == 7) {
#pragma unroll
        for (int j = 0; j < 8; ++j) { ba[j] = ha[j]; bb[j] = hb[j]; }
    } else {
        lds_read8(&sh[0][w + 1][0][x0], ba);
        lds_read8(&sh[1][w + 1][0][x0], bb);
    }

    // image 1 magnitudes, then image 2 + abs-diff accumulate
    float m1[4][8];
    sobel_mag_row(ta,   a[0], a[1], lane, m1[0]);
    sobel_mag_row(a[0], a[1], a[2], lane, m1[1]);
    sobel_mag_row(a[1], a[2], a[3], lane, m1[2]);
    sobel_mag_row(a[2], a[3], ba,   lane, m1[3]);

    float sum = 0.0f;
    {
        float m2[8];
        sobel_mag_row(tb,   b[0], b[1], lane, m2);
#pragma unroll
        for (int j = 0; j < 8; ++j) sum += fabsf(m1[0][j] - m2[j]);
        sobel_mag_row(b[0], b[1], b[2], lane, m2);
#pragma unroll
        for (int j = 0; j < 8; ++j) sum += fabsf(m1[1][j] - m2[j]);
        sobel_mag_row(b[1], b[2], b[3], lane, m2);
#pragma unroll
        for (int j = 0; j < 8; ++j) sum += fabsf(m1[2][j] - m2[j]);
        sobel_mag_row(b[2], b[3], bb,   lane, m2);
#pragma unroll
        for (int j = 0; j < 8; ++j) sum += fabsf(m1[3][j] - m2[j]);
    }

#pragma unroll
    for (int off = 32; off > 0; off >>= 1) sum += __shfl_down(sum, off);

    if (lane == 0) wave_sums[w] = sum;
    __syncthreads();
    if (t == 0) {
        float s = 0.0f;
#pragma unroll
        for (int i = 0; i < 8; ++i) s += wave_sums[i];
        slots[bid] = s;
    }
}

// Deterministic fixed-order reduction of the 768 per-block partials.
__global__ __launch_bounds__(256) void finalize_kernel(const float* __restrict__ slots,
                                                       float* __restrict__ out) {
    const int t = threadIdx.x;
    const int lane = t & 63;
    const int w = t >> 6;
    float s = 0.0f;
#pragma unroll
    for (int i = 0; i < NBLOCKS / 256; ++i) s += slots[t + i * 256];
#pragma unroll
    for (int off = 32; off > 0; off >>= 1) s += __shfl_down(s, off);
    __shared__ float ws[4];
    if (lane == 0) ws[w] = s;
    __syncthreads();
    if (t == 0) out[0] = ((ws[0] + ws[1]) + (ws[2] + ws[3])) * (1.0f / (float)TOTAL_ELEMS);
}

extern "C" void kernel_launch(void* const* d_in, const int* in_sizes, int n_in,
                              void* d_out, int out_size, void* d_ws, size_t ws_size,
                              hipStream_t stream) {
    const float* img1 = (const float*)d_in[0];
    const float* img2 = (const float*)d_in[1];
    float* out = (float*)d_out;
    float* slots = (float*)d_ws;    // 768 floats, fully rewritten every call

    edge_loss_kernel<<<dim3(NBLOCKS), 512, 0, stream>>>(img1, img2, slots);
    finalize_kernel<<<dim3(1), 256, 0, stream>>>(slots, out);
}